// Round 2
// baseline (870.463 us; speedup 1.0000x reference)
//
#include <hip/hip_runtime.h>
#include <hip/hip_bf16.h>

#define BATCH 512
#define SEQ   128
#define EMB   512
#define KCAP  16

// ---------------------------------------------------------------------------
// Tiled fp32 GEMM, C[m][n] = act( sum_k A[m][k] * B[n][k] (+ bias[n]) )
// A: [M, 512] row-major, B: [512, 512] row-major (inner dim contiguous, NT).
// Tile 128x128, BK=16, 256 threads, 8x8 per thread with split-64 col mapping.
// ---------------------------------------------------------------------------
template<bool EPI_BIAS_RELU>
__global__ __launch_bounds__(256, 2)
void gemm_bt(const float* __restrict__ A, const float* __restrict__ B,
             const float* __restrict__ bias, float* __restrict__ C) {
    __shared__ float As[16][128];
    __shared__ float Bs[16][128];
    const int tid = threadIdx.x;
    const long row0 = (long)blockIdx.x * 128;
    const long col0 = (long)blockIdx.y * 128;

    // staging: each thread loads 2 float4 of A and 2 float4 of B
    const int sr = tid >> 1;          // 0..127: row within tile
    const int sk = (tid & 1) * 8;     // 0 or 8: k offset
    const float* Ap = A + (row0 + sr) * EMB + sk;
    const float* Bp = B + (col0 + sr) * EMB + sk;

    const int tx = tid & 15;          // col group
    const int ty = tid >> 4;          // row group

    float acc[8][8];
    #pragma unroll
    for (int i = 0; i < 8; ++i)
        #pragma unroll
        for (int j = 0; j < 8; ++j) acc[i][j] = 0.f;

    for (int kt = 0; kt < EMB; kt += 16) {
        const float4 a0 = *(const float4*)(Ap + kt);
        const float4 a1 = *(const float4*)(Ap + kt + 4);
        const float4 b0 = *(const float4*)(Bp + kt);
        const float4 b1 = *(const float4*)(Bp + kt + 4);
        __syncthreads();   // previous iteration's LDS reads done
        As[sk+0][sr] = a0.x; As[sk+1][sr] = a0.y; As[sk+2][sr] = a0.z; As[sk+3][sr] = a0.w;
        As[sk+4][sr] = a1.x; As[sk+5][sr] = a1.y; As[sk+6][sr] = a1.z; As[sk+7][sr] = a1.w;
        Bs[sk+0][sr] = b0.x; Bs[sk+1][sr] = b0.y; Bs[sk+2][sr] = b0.z; Bs[sk+3][sr] = b0.w;
        Bs[sk+4][sr] = b1.x; Bs[sk+5][sr] = b1.y; Bs[sk+6][sr] = b1.z; Bs[sk+7][sr] = b1.w;
        __syncthreads();
        #pragma unroll
        for (int kk = 0; kk < 16; ++kk) {
            const float4 x0 = *(const float4*)&As[kk][ty * 4];
            const float4 x1 = *(const float4*)&As[kk][64 + ty * 4];
            const float4 y0 = *(const float4*)&Bs[kk][tx * 4];
            const float4 y1 = *(const float4*)&Bs[kk][64 + tx * 4];
            const float xs[8] = {x0.x, x0.y, x0.z, x0.w, x1.x, x1.y, x1.z, x1.w};
            const float ys[8] = {y0.x, y0.y, y0.z, y0.w, y1.x, y1.y, y1.z, y1.w};
            #pragma unroll
            for (int i = 0; i < 8; ++i)
                #pragma unroll
                for (int j = 0; j < 8; ++j) acc[i][j] += xs[i] * ys[j];
        }
    }

    #pragma unroll
    for (int i = 0; i < 8; ++i) {
        const long row = row0 + ((i >> 2) << 6) + ty * 4 + (i & 3);
        #pragma unroll
        for (int jh = 0; jh < 2; ++jh) {
            const long col = col0 + (jh << 6) + tx * 4;
            float4 r;
            r.x = acc[i][jh * 4 + 0];
            r.y = acc[i][jh * 4 + 1];
            r.z = acc[i][jh * 4 + 2];
            r.w = acc[i][jh * 4 + 3];
            if (EPI_BIAS_RELU) {
                const float4 bb = *(const float4*)(bias + col);
                r.x = fmaxf(r.x + bb.x, 0.f);
                r.y = fmaxf(r.y + bb.y, 0.f);
                r.z = fmaxf(r.z + bb.z, 0.f);
                r.w = fmaxf(r.w + bb.w, 0.f);
            }
            *(float4*)(C + row * 512 + col) = r;
        }
    }
}

// ---------------------------------------------------------------------------
// Routing: one block per batch, 512 threads (8 waves).
// ---------------------------------------------------------------------------
__device__ __forceinline__ float dot4(const float4 a, const float4 b) {
    return a.x * b.x + a.y * b.y + a.z * b.z + a.w * b.w;
}

__global__ __launch_bounds__(512, 4)
void routing_kernel(const float* __restrict__ lcn, const float* __restrict__ Binit,
                    const int* __restrict__ valid, float* __restrict__ Uout) {
    __shared__ float sBc[KCAP][SEQ];    // logits  [k][s]   8 KB
    __shared__ float sWt[SEQ][KCAP];    // masked softmax, transposed [s][k]  8 KB
    __shared__ float sU[KCAP][EMB];     // Z then squashed U  32 KB
    __shared__ float smask[SEQ];

    const int b    = blockIdx.x;
    const int tid  = threadIdx.x;
    const int lane = tid & 63;
    const int w    = tid >> 6;          // wave id 0..7
    const int e0   = (tid & 127) * 4;   // e chunk
    const int k0   = (tid >> 7) * 4;    // k chunk
    const float* lcb = lcn + (size_t)b * (SEQ * EMB);

    for (int i = tid; i < KCAP * SEQ; i += 512)
        ((float*)sBc)[i] = Binit[(size_t)b * (KCAP * SEQ) + i];
    if (tid < SEQ) smask[tid] = (valid[b * SEQ + tid] != 0) ? 1.0f : 0.0f;
    __syncthreads();

    for (int it = 0; it < 3; ++it) {
        // ---- softmax over k at each s (denominator unmasked), then mask ----
        if (tid < SEQ) {
            const int s = tid;
            float mx = sBc[0][s];
            #pragma unroll
            for (int k = 1; k < KCAP; ++k) mx = fmaxf(mx, sBc[k][s]);
            float ex[KCAP];
            float sum = 0.f;
            #pragma unroll
            for (int k = 0; k < KCAP; ++k) { ex[k] = expf(sBc[k][s] - mx); sum += ex[k]; }
            const float inv = smask[s] / sum;
            #pragma unroll
            for (int k = 0; k < KCAP; ++k) sWt[s][k] = ex[k] * inv;
        }
        __syncthreads();

        // ---- Z[k][e] = sum_s W[k][s] * lc[s][e] ; thread owns 4k x 4e ----
        float acc[4][4];
        #pragma unroll
        for (int i = 0; i < 4; ++i)
            #pragma unroll
            for (int j = 0; j < 4; ++j) acc[i][j] = 0.f;
        #pragma unroll 4
        for (int s = 0; s < SEQ; ++s) {
            const float4 v  = *(const float4*)(lcb + s * EMB + e0);
            const float4 wv = *(const float4*)&sWt[s][k0];
            const float wa[4] = {wv.x, wv.y, wv.z, wv.w};
            const float va[4] = {v.x, v.y, v.z, v.w};
            #pragma unroll
            for (int ki = 0; ki < 4; ++ki)
                #pragma unroll
                for (int j = 0; j < 4; ++j) acc[ki][j] += wa[ki] * va[j];
        }
        #pragma unroll
        for (int ki = 0; ki < 4; ++ki) {
            float4 r;
            r.x = acc[ki][0]; r.y = acc[ki][1]; r.z = acc[ki][2]; r.w = acc[ki][3];
            *(float4*)&sU[k0 + ki][e0] = r;
        }
        __syncthreads();

        // ---- squash each capsule row; wave w handles k = 2w, 2w+1 ----
        #pragma unroll
        for (int kk = 2 * w; kk <= 2 * w + 1; ++kk) {
            float4 z0 = *(const float4*)&sU[kk][lane * 4];
            float4 z1 = *(const float4*)&sU[kk][256 + lane * 4];
            float p = dot4(z0, z0) + dot4(z1, z1);
            #pragma unroll
            for (int m = 32; m >= 1; m >>= 1) p += __shfl_xor(p, m, 64);
            const float scale = p / (1.0f + p) / sqrtf(p + 1e-9f);
            z0.x *= scale; z0.y *= scale; z0.z *= scale; z0.w *= scale;
            z1.x *= scale; z1.y *= scale; z1.z *= scale; z1.w *= scale;
            *(float4*)&sU[kk][lane * 4] = z0;
            *(float4*)&sU[kk][256 + lane * 4] = z1;
        }
        __syncthreads();

        // ---- B update: Bc[k][s] += sum_e lc[s][e] * U[k][e]  (iters 0,1) ----
        if (it < 2) {
            const int ka = 2 * w, kb = 2 * w + 1;
            const float4 ua0 = *(const float4*)&sU[ka][lane * 4];
            const float4 ua1 = *(const float4*)&sU[ka][256 + lane * 4];
            const float4 ub0 = *(const float4*)&sU[kb][lane * 4];
            const float4 ub1 = *(const float4*)&sU[kb][256 + lane * 4];
            #pragma unroll 2
            for (int s = 0; s < SEQ; ++s) {
                const float4 l0 = *(const float4*)(lcb + s * EMB + lane * 4);
                const float4 l1 = *(const float4*)(lcb + s * EMB + 256 + lane * 4);
                float pa = dot4(l0, ua0) + dot4(l1, ua1);
                float pb = dot4(l0, ub0) + dot4(l1, ub1);
                #pragma unroll
                for (int m = 32; m >= 1; m >>= 1) {
                    pa += __shfl_xor(pa, m, 64);
                    pb += __shfl_xor(pb, m, 64);
                }
                if (lane == 0) {
                    sBc[ka][s] += pa;
                    sBc[kb][s] += pb;
                }
            }
            __syncthreads();
        }
    }

    // ---- write U (squashed, last iter) to workspace ----
    for (int i = tid; i < KCAP * EMB; i += 512)
        Uout[(size_t)b * (KCAP * EMB) + i] = ((const float*)sU)[i];
}

// ---------------------------------------------------------------------------
extern "C" void kernel_launch(void* const* d_in, const int* in_sizes, int n_in,
                              void* d_out, int out_size, void* d_ws, size_t ws_size,
                              hipStream_t stream) {
    const float* lc    = (const float*)d_in[0];  // [512,128,512]
    const float* Binit = (const float*)d_in[1];  // [512,16,128]
    const float* W_S   = (const float*)d_in[2];  // [512,512]
    const float* W_L   = (const float*)d_in[3];  // [512,512]
    const float* b_L   = (const float*)d_in[4];  // [512]
    const int*   valid = (const int*)d_in[5];    // [512,128]
    float* out = (float*)d_out;                  // [512,16,512]

    // workspace layout: lc_new [65536,512] f32 (128 MiB floats), U [8192,512] f32
    const size_t lcn_elems = (size_t)BATCH * SEQ * EMB;          // 33,554,432
    const size_t u_elems   = (size_t)BATCH * KCAP * EMB;         //  4,194,304
    if (ws_size < (lcn_elems + u_elems) * sizeof(float)) return; // fail cleanly
    float* lcn = (float*)d_ws;
    float* Uws = lcn + lcn_elems;

    // 1) lc_new = low_capsule @ W_S^T   (M=65536)
    gemm_bt<false><<<dim3(512, 4), 256, 0, stream>>>(lc, W_S, nullptr, lcn);
    // 2) dynamic routing per batch
    routing_kernel<<<dim3(BATCH), 512, 0, stream>>>(lcn, Binit, valid, Uws);
    // 3) out = relu(U @ W_L^T + b_L)    (M=8192)
    gemm_bt<true><<<dim3(64, 4), 256, 0, stream>>>(Uws, W_L, b_L, out);
}

// Round 4
// 603.307 us; speedup vs baseline: 1.4428x; 1.4428x over previous
//
#include <hip/hip_runtime.h>
#include <hip/hip_bf16.h>

#define BATCH 512
#define SEQ   128
#define EMB   512
#define KCAP  16

typedef __attribute__((ext_vector_type(4))) float f32x4;
typedef __attribute__((ext_vector_type(8))) short s16x8;   // 8 bf16 = 4 VGPR

// f32 -> bf16 round-to-nearest-even
__device__ __forceinline__ unsigned short f2bf(float x) {
    union { float f; unsigned int u; } v; v.f = x;
    unsigned int r = v.u + 0x7fff + ((v.u >> 16) & 1);
    return (unsigned short)(r >> 16);
}
__device__ __forceinline__ float bf2f(unsigned short b) {
    union { float f; unsigned int u; } v; v.u = ((unsigned int)b) << 16;
    return v.f;
}
__device__ __forceinline__ void cvt8(const float* f, s16x8& h, s16x8& l) {
    #pragma unroll
    for (int j = 0; j < 8; ++j) {
        unsigned short hb = f2bf(f[j]);
        h[j] = (short)hb;
        l[j] = (short)f2bf(f[j] - bf2f(hb));
    }
}

// swizzled element offset inside a [128][32]-bf16 tile; chunk = 8-bf16 (16B) unit
__device__ __forceinline__ int swz(int row, int chunk) {
    return row * 32 + ((chunk ^ ((row >> 1) & 3)) << 3);
}

// ---------------------------------------------------------------------------
// Split-bf16 MFMA GEMM: C[m][n] = act( sum_k A[m][k]*B[n][k] (+bias) ), N=K=512.
// A = Ah+Al, B = Bh+Bl (bf16 hi/lo); acc += AhBh + AlBh + AhBl (AlBl dropped,
// rel err ~2^-16). 128x128 tile, BK=32, 4 waves in 2x2, 16x16x32 MFMA.
// Grid: 1D, m = bx>>2, n = bx&3 (4 consecutive blocks share A rows).
// ---------------------------------------------------------------------------
template<bool EPI_BIAS_RELU>
__global__ __launch_bounds__(256, 2)
void gemm_mfma(const float* __restrict__ A, const float* __restrict__ B,
               const float* __restrict__ bias, float* __restrict__ C) {
    __shared__ short lsAh[128 * 32], lsAl[128 * 32];
    __shared__ short lsBh[128 * 32], lsBl[128 * 32];

    const int tid  = threadIdx.x;
    const int lane = tid & 63;
    const int w    = tid >> 6;
    const int wm   = (w & 1) * 64;      // wave row offset in tile
    const int wn   = (w >> 1) * 64;     // wave col offset in tile
    const size_t row0 = (size_t)(blockIdx.x >> 2) * 128;
    const int    col0 = (int)(blockIdx.x & 3) * 128;

    // staging: thread -> (row, 16-wide k-half)
    const int srow = tid >> 1;
    const int skh  = tid & 1;           // k-half: 0 or 1 (16 floats)
    const int cb   = skh * 2;           // first output chunk
    const float* Ap = A + (row0 + srow) * 512 + skh * 16;
    const float* Bp = B + (size_t)(col0 + srow) * 512 + skh * 16;

    f32x4 acc[4][4];
    #pragma unroll
    for (int i = 0; i < 4; ++i)
        #pragma unroll
        for (int j = 0; j < 4; ++j) acc[i][j] = (f32x4){0.f, 0.f, 0.f, 0.f};

    for (int kt = 0; kt < 512; kt += 32) {
        float fa[16], fb[16];
        *(float4*)&fa[0]  = *(const float4*)(Ap + kt);
        *(float4*)&fa[4]  = *(const float4*)(Ap + kt + 4);
        *(float4*)&fa[8]  = *(const float4*)(Ap + kt + 8);
        *(float4*)&fa[12] = *(const float4*)(Ap + kt + 12);
        *(float4*)&fb[0]  = *(const float4*)(Bp + kt);
        *(float4*)&fb[4]  = *(const float4*)(Bp + kt + 4);
        *(float4*)&fb[8]  = *(const float4*)(Bp + kt + 8);
        *(float4*)&fb[12] = *(const float4*)(Bp + kt + 12);

        __syncthreads();   // previous iteration's LDS reads complete
        s16x8 h, l;
        cvt8(fa,     h, l); *(s16x8*)&lsAh[swz(srow, cb)]     = h; *(s16x8*)&lsAl[swz(srow, cb)]     = l;
        cvt8(fa + 8, h, l); *(s16x8*)&lsAh[swz(srow, cb + 1)] = h; *(s16x8*)&lsAl[swz(srow, cb + 1)] = l;
        cvt8(fb,     h, l); *(s16x8*)&lsBh[swz(srow, cb)]     = h; *(s16x8*)&lsBl[swz(srow, cb)]     = l;
        cvt8(fb + 8, h, l); *(s16x8*)&lsBh[swz(srow, cb + 1)] = h; *(s16x8*)&lsBl[swz(srow, cb + 1)] = l;
        __syncthreads();

        s16x8 ah[4], al[4], bh[4], bl[4];
        const int c = lane >> 4;
        #pragma unroll
        for (int mi = 0; mi < 4; ++mi) {
            const int r = wm + mi * 16 + (lane & 15);
            ah[mi] = *(const s16x8*)&lsAh[swz(r, c)];
            al[mi] = *(const s16x8*)&lsAl[swz(r, c)];
        }
        #pragma unroll
        for (int ni = 0; ni < 4; ++ni) {
            const int r = wn + ni * 16 + (lane & 15);
            bh[ni] = *(const s16x8*)&lsBh[swz(r, c)];
            bl[ni] = *(const s16x8*)&lsBl[swz(r, c)];
        }
        #pragma unroll
        for (int mi = 0; mi < 4; ++mi)
            #pragma unroll
            for (int ni = 0; ni < 4; ++ni) {
                acc[mi][ni] = __builtin_amdgcn_mfma_f32_16x16x32_bf16(ah[mi], bh[ni], acc[mi][ni], 0, 0, 0);
                acc[mi][ni] = __builtin_amdgcn_mfma_f32_16x16x32_bf16(al[mi], bh[ni], acc[mi][ni], 0, 0, 0);
                acc[mi][ni] = __builtin_amdgcn_mfma_f32_16x16x32_bf16(ah[mi], bl[ni], acc[mi][ni], 0, 0, 0);
            }
    }

    // epilogue: C/D layout col=lane&15, row=(lane>>4)*4+reg  [m89-verified]
    #pragma unroll
    for (int ni = 0; ni < 4; ++ni) {
        const int gc = col0 + wn + ni * 16 + (lane & 15);
        float bv = 0.f;
        if (EPI_BIAS_RELU) bv = bias[gc];
        #pragma unroll
        for (int mi = 0; mi < 4; ++mi) {
            const size_t gr = row0 + wm + mi * 16 + ((lane >> 4) << 2);
            #pragma unroll
            for (int r = 0; r < 4; ++r) {
                float v = acc[mi][ni][r];
                if (EPI_BIAS_RELU) v = fmaxf(v + bv, 0.f);
                C[(gr + r) * 512 + gc] = v;
            }
        }
    }
}

// ---------------------------------------------------------------------------
// Routing: one block per batch, 512 threads (8 waves). (unchanged)
// ---------------------------------------------------------------------------
__device__ __forceinline__ float dot4(const float4 a, const float4 b) {
    return a.x * b.x + a.y * b.y + a.z * b.z + a.w * b.w;
}

__global__ __launch_bounds__(512, 4)
void routing_kernel(const float* __restrict__ lcn, const float* __restrict__ Binit,
                    const int* __restrict__ valid, float* __restrict__ Uout) {
    __shared__ float sBc[KCAP][SEQ];
    __shared__ float sWt[SEQ][KCAP];
    __shared__ float sU[KCAP][EMB];
    __shared__ float smask[SEQ];

    const int b    = blockIdx.x;
    const int tid  = threadIdx.x;
    const int lane = tid & 63;
    const int w    = tid >> 6;
    const int e0   = (tid & 127) * 4;
    const int k0   = (tid >> 7) * 4;
    const float* lcb = lcn + (size_t)b * (SEQ * EMB);

    for (int i = tid; i < KCAP * SEQ; i += 512)
        ((float*)sBc)[i] = Binit[(size_t)b * (KCAP * SEQ) + i];
    if (tid < SEQ) smask[tid] = (valid[b * SEQ + tid] != 0) ? 1.0f : 0.0f;
    __syncthreads();

    for (int it = 0; it < 3; ++it) {
        if (tid < SEQ) {
            const int s = tid;
            float mx = sBc[0][s];
            #pragma unroll
            for (int k = 1; k < KCAP; ++k) mx = fmaxf(mx, sBc[k][s]);
            float ex[KCAP];
            float sum = 0.f;
            #pragma unroll
            for (int k = 0; k < KCAP; ++k) { ex[k] = expf(sBc[k][s] - mx); sum += ex[k]; }
            const float inv = smask[s] / sum;
            #pragma unroll
            for (int k = 0; k < KCAP; ++k) sWt[s][k] = ex[k] * inv;
        }
        __syncthreads();

        float acc[4][4];
        #pragma unroll
        for (int i = 0; i < 4; ++i)
            #pragma unroll
            for (int j = 0; j < 4; ++j) acc[i][j] = 0.f;
        #pragma unroll 4
        for (int s = 0; s < SEQ; ++s) {
            const float4 v  = *(const float4*)(lcb + s * EMB + e0);
            const float4 wv = *(const float4*)&sWt[s][k0];
            const float wa[4] = {wv.x, wv.y, wv.z, wv.w};
            const float va[4] = {v.x, v.y, v.z, v.w};
            #pragma unroll
            for (int ki = 0; ki < 4; ++ki)
                #pragma unroll
                for (int j = 0; j < 4; ++j) acc[ki][j] += wa[ki] * va[j];
        }
        #pragma unroll
        for (int ki = 0; ki < 4; ++ki) {
            float4 r;
            r.x = acc[ki][0]; r.y = acc[ki][1]; r.z = acc[ki][2]; r.w = acc[ki][3];
            *(float4*)&sU[k0 + ki][e0] = r;
        }
        __syncthreads();

        #pragma unroll
        for (int kk = 2 * w; kk <= 2 * w + 1; ++kk) {
            float4 z0 = *(const float4*)&sU[kk][lane * 4];
            float4 z1 = *(const float4*)&sU[kk][256 + lane * 4];
            float p = dot4(z0, z0) + dot4(z1, z1);
            #pragma unroll
            for (int m = 32; m >= 1; m >>= 1) p += __shfl_xor(p, m, 64);
            const float scale = p / (1.0f + p) / sqrtf(p + 1e-9f);
            z0.x *= scale; z0.y *= scale; z0.z *= scale; z0.w *= scale;
            z1.x *= scale; z1.y *= scale; z1.z *= scale; z1.w *= scale;
            *(float4*)&sU[kk][lane * 4] = z0;
            *(float4*)&sU[kk][256 + lane * 4] = z1;
        }
        __syncthreads();

        if (it < 2) {
            const int ka = 2 * w, kb = 2 * w + 1;
            const float4 ua0 = *(const float4*)&sU[ka][lane * 4];
            const float4 ua1 = *(const float4*)&sU[ka][256 + lane * 4];
            const float4 ub0 = *(const float4*)&sU[kb][lane * 4];
            const float4 ub1 = *(const float4*)&sU[kb][256 + lane * 4];
            #pragma unroll 2
            for (int s = 0; s < SEQ; ++s) {
                const float4 l0 = *(const float4*)(lcb + s * EMB + lane * 4);
                const float4 l1 = *(const float4*)(lcb + s * EMB + 256 + lane * 4);
                float pa = dot4(l0, ua0) + dot4(l1, ua1);
                float pb = dot4(l0, ub0) + dot4(l1, ub1);
                #pragma unroll
                for (int m = 32; m >= 1; m >>= 1) {
                    pa += __shfl_xor(pa, m, 64);
                    pb += __shfl_xor(pb, m, 64);
                }
                if (lane == 0) {
                    sBc[ka][s] += pa;
                    sBc[kb][s] += pb;
                }
            }
            __syncthreads();
        }
    }

    for (int i = tid; i < KCAP * EMB; i += 512)
        Uout[(size_t)b * (KCAP * EMB) + i] = ((const float*)sU)[i];
}

// ---------------------------------------------------------------------------
extern "C" void kernel_launch(void* const* d_in, const int* in_sizes, int n_in,
                              void* d_out, int out_size, void* d_ws, size_t ws_size,
                              hipStream_t stream) {
    const float* lc    = (const float*)d_in[0];  // [512,128,512]
    const float* Binit = (const float*)d_in[1];  // [512,16,128]
    const float* W_S   = (const float*)d_in[2];  // [512,512]
    const float* W_L   = (const float*)d_in[3];  // [512,512]
    const float* b_L   = (const float*)d_in[4];  // [512]
    const int*   valid = (const int*)d_in[5];    // [512,128]
    float* out = (float*)d_out;                  // [512,16,512]

    const size_t lcn_elems = (size_t)BATCH * SEQ * EMB;
    const size_t u_elems   = (size_t)BATCH * KCAP * EMB;
    if (ws_size < (lcn_elems + u_elems) * sizeof(float)) return;
    float* lcn = (float*)d_ws;
    float* Uws = lcn + lcn_elems;

    // 1) lc_new = low_capsule @ W_S^T  (M=65536 -> 512 m-blocks x 4 n-blocks)
    gemm_mfma<false><<<2048, 256, 0, stream>>>(lc, W_S, nullptr, lcn);
    // 2) dynamic routing per batch
    routing_kernel<<<BATCH, 512, 0, stream>>>(lcn, Binit, valid, Uws);
    // 3) out = relu(U @ W_L^T + b_L)   (M=8192 -> 64 x 4)
    gemm_mfma<true><<<256, 256, 0, stream>>>(Uws, W_L, b_L, out);
}

// Round 11
// 547.060 us; speedup vs baseline: 1.5912x; 1.1028x over previous
//
#include <hip/hip_runtime.h>
#include <hip/hip_bf16.h>

#define BATCH 512
#define SEQ   128
#define EMB   512
#define KCAP  16

typedef __attribute__((ext_vector_type(4))) float f32x4;
typedef __attribute__((ext_vector_type(8))) short s16x8;
typedef __attribute__((ext_vector_type(4))) unsigned short u16x4;
typedef __attribute__((ext_vector_type(8))) unsigned short u16x8;

__device__ __forceinline__ unsigned short f2bf(float x) {
    union { float f; unsigned int u; } v; v.f = x;
    unsigned int r = v.u + 0x7fff + ((v.u >> 16) & 1);
    return (unsigned short)(r >> 16);
}
__device__ __forceinline__ float bf2f(unsigned short b) {
    union { float f; unsigned int u; } v; v.u = ((unsigned int)b) << 16;
    return v.f;
}
__device__ __forceinline__ void cvt8(const float* f, s16x8& h, s16x8& l) {
    #pragma unroll
    for (int j = 0; j < 8; ++j) {
        unsigned short hb = f2bf(f[j]);
        h[j] = (short)hb;
        l[j] = (short)f2bf(f[j] - bf2f(hb));
    }
}
__device__ __forceinline__ float dot4(const float4 a, const float4 b) {
    return a.x * b.x + a.y * b.y + a.z * b.z + a.w * b.w;
}

// A-tile swizzled ushort offset in [128][32]; chunk = 8-elem (16B) unit
__device__ __forceinline__ int swz(int row, int chunk) {
    return row * 32 + ((chunk ^ ((row >> 1) & 3)) << 3);
}

// ---------------------------------------------------------------------------
// cvt_pack: f32 [rows][512] -> interleaved hi/lo bf16: per 8-elem chunk c:
// out[c*16 .. c*16+7] = hi8, out[c*16+8 .. +15] = lo8.
// ---------------------------------------------------------------------------
__global__ void cvt_pack(const float* __restrict__ in, unsigned short* __restrict__ out, int nch) {
    const int c = blockIdx.x * 256 + threadIdx.x;
    if (c >= nch) return;
    float f[8];
    *(float4*)&f[0] = *(const float4*)(in + c * 8);
    *(float4*)&f[4] = *(const float4*)(in + c * 8 + 4);
    u16x8 h, l;
    #pragma unroll
    for (int j = 0; j < 8; ++j) {
        unsigned short hb = f2bf(f[j]);
        h[j] = hb;
        l[j] = f2bf(f[j] - bf2f(hb));
    }
    *(u16x8*)(out + c * 16) = h;
    *(u16x8*)(out + c * 16 + 8) = l;
}

// ---------------------------------------------------------------------------
// GEMM1: C[m][n] = sum_k A[m][k]*B[n][k]; A f32 (cvt in-kernel), B packed
// hi/lo bf16 interleaved. 128x128 tile, BK=32, 4 waves (2x2 of 64x64),
// 3-product split-bf16 MFMA. Grid: m = bx>>2, n = bx&3.
// ---------------------------------------------------------------------------
__global__ __launch_bounds__(256, 2)
void gemm_f32a(const float* __restrict__ A, const unsigned short* __restrict__ pkB,
               float* __restrict__ C) {
    __shared__ short lsAh[128 * 32], lsAl[128 * 32];
    __shared__ unsigned short lsB[128 * 64];   // [row][s3][8], s3 = swizzled chunk16

    const int tid  = threadIdx.x;
    const int lane = tid & 63;
    const int w    = tid >> 6;
    const int wm   = (w & 1) * 64;
    const int wn   = (w >> 1) * 64;
    const size_t row0 = (size_t)(blockIdx.x >> 2) * 128;
    const int    col0 = (int)(blockIdx.x & 3) * 128;

    const int srow = tid >> 1;
    const int skh  = tid & 1;
    const int cb   = skh * 2;
    const float* Ap = A + (row0 + srow) * 512 + skh * 16;

    // B staging: 4 slot16s per thread, slot = i*256+tid; swizzle s3^(row&7)
    int bo[4], so[4];
    #pragma unroll
    for (int i = 0; i < 4; ++i) {
        const int slot = i * 256 + tid;
        const int br = slot >> 3, s3 = slot & 7;
        const int cn = s3 ^ (br & 7);
        bo[i] = (col0 + br) * 1024 + (cn >> 1) * 16 + (cn & 1) * 8;  // ushort idx
        so[i] = slot * 8;
    }

    f32x4 acc[4][4];
    #pragma unroll
    for (int i = 0; i < 4; ++i)
        #pragma unroll
        for (int j = 0; j < 4; ++j) acc[i][j] = (f32x4){0.f, 0.f, 0.f, 0.f};

    for (int kt = 0; kt < 512; kt += 32) {
        float fa[16];
        *(float4*)&fa[0]  = *(const float4*)(Ap + kt);
        *(float4*)&fa[4]  = *(const float4*)(Ap + kt + 4);
        *(float4*)&fa[8]  = *(const float4*)(Ap + kt + 8);
        *(float4*)&fa[12] = *(const float4*)(Ap + kt + 12);
        u16x8 bq[4];
        #pragma unroll
        for (int i = 0; i < 4; ++i) bq[i] = *(const u16x8*)(pkB + bo[i] + kt * 2);

        __syncthreads();
        s16x8 h, l;
        cvt8(fa,     h, l); *(s16x8*)&lsAh[swz(srow, cb)]     = h; *(s16x8*)&lsAl[swz(srow, cb)]     = l;
        cvt8(fa + 8, h, l); *(s16x8*)&lsAh[swz(srow, cb + 1)] = h; *(s16x8*)&lsAl[swz(srow, cb + 1)] = l;
        #pragma unroll
        for (int i = 0; i < 4; ++i) *(u16x8*)&lsB[so[i]] = bq[i];
        __syncthreads();

        const int c = lane >> 4;
        s16x8 ah[4], al[4];
        #pragma unroll
        for (int mi = 0; mi < 4; ++mi) {
            const int r = wm + mi * 16 + (lane & 15);
            ah[mi] = *(const s16x8*)&lsAh[swz(r, c)];
            al[mi] = *(const s16x8*)&lsAl[swz(r, c)];
        }
        #pragma unroll
        for (int ni = 0; ni < 4; ++ni) {
            const int r = wn + ni * 16 + (lane & 15);
            const s16x8 bh = *(const s16x8*)&lsB[r * 64 + (((2 * c)     ^ (r & 7)) << 3)];
            const s16x8 bl = *(const s16x8*)&lsB[r * 64 + (((2 * c + 1) ^ (r & 7)) << 3)];
            #pragma unroll
            for (int mi = 0; mi < 4; ++mi) {
                acc[mi][ni] = __builtin_amdgcn_mfma_f32_16x16x32_bf16(ah[mi], bh, acc[mi][ni], 0, 0, 0);
                acc[mi][ni] = __builtin_amdgcn_mfma_f32_16x16x32_bf16(al[mi], bh, acc[mi][ni], 0, 0, 0);
                acc[mi][ni] = __builtin_amdgcn_mfma_f32_16x16x32_bf16(ah[mi], bl, acc[mi][ni], 0, 0, 0);
            }
        }
    }

    #pragma unroll
    for (int ni = 0; ni < 4; ++ni) {
        const int gc = col0 + wn + ni * 16 + (lane & 15);
        #pragma unroll
        for (int mi = 0; mi < 4; ++mi) {
            const size_t gr = row0 + wm + mi * 16 + ((lane >> 4) << 2);
            #pragma unroll
            for (int r = 0; r < 4; ++r) C[(gr + r) * 512 + gc] = acc[mi][ni][r];
        }
    }
}

// ---------------------------------------------------------------------------
// GEMM2: A bf16 (hi only), B packed hi/lo, bias+relu epilogue. 2-product MFMA.
// ---------------------------------------------------------------------------
__global__ __launch_bounds__(256, 2)
void gemm_bf16a(const unsigned short* __restrict__ A, const unsigned short* __restrict__ pkB,
                const float* __restrict__ bias, float* __restrict__ C) {
    __shared__ unsigned short lsA[128 * 32];
    __shared__ unsigned short lsB[128 * 64];

    const int tid  = threadIdx.x;
    const int lane = tid & 63;
    const int w    = tid >> 6;
    const int wm   = (w & 1) * 64;
    const int wn   = (w >> 1) * 64;
    const size_t row0 = (size_t)(blockIdx.x >> 2) * 128;
    const int    col0 = (int)(blockIdx.x & 3) * 128;

    const int srow = tid >> 1;
    const int skh  = tid & 1;
    const int cb   = skh * 2;
    const unsigned short* Up = A + (row0 + srow) * 512 + skh * 16;

    int bo[4], so[4];
    #pragma unroll
    for (int i = 0; i < 4; ++i) {
        const int slot = i * 256 + tid;
        const int br = slot >> 3, s3 = slot & 7;
        const int cn = s3 ^ (br & 7);
        bo[i] = (col0 + br) * 1024 + (cn >> 1) * 16 + (cn & 1) * 8;
        so[i] = slot * 8;
    }

    f32x4 acc[4][4];
    #pragma unroll
    for (int i = 0; i < 4; ++i)
        #pragma unroll
        for (int j = 0; j < 4; ++j) acc[i][j] = (f32x4){0.f, 0.f, 0.f, 0.f};

    for (int kt = 0; kt < 512; kt += 32) {
        const u16x8 a0 = *(const u16x8*)(Up + kt);
        const u16x8 a1 = *(const u16x8*)(Up + kt + 8);
        u16x8 bq[4];
        #pragma unroll
        for (int i = 0; i < 4; ++i) bq[i] = *(const u16x8*)(pkB + bo[i] + kt * 2);

        __syncthreads();
        *(u16x8*)&lsA[swz(srow, cb)]     = a0;
        *(u16x8*)&lsA[swz(srow, cb + 1)] = a1;
        #pragma unroll
        for (int i = 0; i < 4; ++i) *(u16x8*)&lsB[so[i]] = bq[i];
        __syncthreads();

        const int c = lane >> 4;
        s16x8 ah[4];
        #pragma unroll
        for (int mi = 0; mi < 4; ++mi)
            ah[mi] = *(const s16x8*)&lsA[swz(wm + mi * 16 + (lane & 15), c)];
        #pragma unroll
        for (int ni = 0; ni < 4; ++ni) {
            const int r = wn + ni * 16 + (lane & 15);
            const s16x8 bh = *(const s16x8*)&lsB[r * 64 + (((2 * c)     ^ (r & 7)) << 3)];
            const s16x8 bl = *(const s16x8*)&lsB[r * 64 + (((2 * c + 1) ^ (r & 7)) << 3)];
            #pragma unroll
            for (int mi = 0; mi < 4; ++mi) {
                acc[mi][ni] = __builtin_amdgcn_mfma_f32_16x16x32_bf16(ah[mi], bh, acc[mi][ni], 0, 0, 0);
                acc[mi][ni] = __builtin_amdgcn_mfma_f32_16x16x32_bf16(ah[mi], bl, acc[mi][ni], 0, 0, 0);
            }
        }
    }

    #pragma unroll
    for (int ni = 0; ni < 4; ++ni) {
        const int gc = col0 + wn + ni * 16 + (lane & 15);
        const float bv = bias[gc];
        #pragma unroll
        for (int mi = 0; mi < 4; ++mi) {
            const size_t gr = row0 + wm + mi * 16 + ((lane >> 4) << 2);
            #pragma unroll
            for (int r = 0; r < 4; ++r)
                C[(gr + r) * 512 + gc] = fmaxf(acc[mi][ni][r] + bv, 0.f);
        }
    }
}

// ---------------------------------------------------------------------------
// Routing v2: 1 block/batch, 512 thr. lc staged in 16-s LDS slabs; per slab:
// B-update (U in regs) -> softmax (256 thr, shfl) -> Z accumulate (regs).
// Writes U as bf16.
// ---------------------------------------------------------------------------
__global__ __launch_bounds__(512, 2)
void routing_v2(const float* __restrict__ lcn, const float* __restrict__ Binit,
                const int* __restrict__ valid, unsigned short* __restrict__ Uh) {
    __shared__ float sBc[KCAP][SEQ];     // 8 KB
    __shared__ float sWt[16][KCAP];      // 1 KB (slab-local W)
    __shared__ float sU[KCAP][EMB];      // 32 KB
    __shared__ float sLc[16][EMB];       // 32 KB
    __shared__ float smask[SEQ];

    const int b = blockIdx.x, t = threadIdx.x;
    const int lane = t & 63, w = t >> 6;
    const float* lcb = lcn + (size_t)b * (SEQ * EMB);

    for (int i = t; i < KCAP * SEQ; i += 512)
        ((float*)sBc)[i] = Binit[(size_t)b * (KCAP * SEQ) + i];
    if (t < SEQ) smask[t] = (valid[b * SEQ + t] != 0) ? 1.0f : 0.0f;
    __syncthreads();

    const int k0 = (t >> 7) * 4;      // Z: 4 capsules per thread
    const int e0 = (t & 127) * 4;     // Z: 4 e per thread
    const int ka = 2 * w, kb = 2 * w + 1;

    for (int it = 0; it < 3; ++it) {
        float4 ua0, ua1, ub0, ub1;
        if (it > 0) {   // previous iter's U for B-update
            ua0 = *(const float4*)&sU[ka][lane * 4];
            ua1 = *(const float4*)&sU[ka][256 + lane * 4];
            ub0 = *(const float4*)&sU[kb][lane * 4];
            ub1 = *(const float4*)&sU[kb][256 + lane * 4];
        }
        f32x4 accZ[4];
        #pragma unroll
        for (int i = 0; i < 4; ++i) accZ[i] = (f32x4){0.f, 0.f, 0.f, 0.f};

        for (int slab = 0; slab < 8; ++slab) {
            {   // stage 16 s rows (32 KB)
                const float4* src = (const float4*)(lcb + slab * 16 * EMB);
                float4* dst = (float4*)sLc;
                #pragma unroll
                for (int j = 0; j < 4; ++j) dst[t + 512 * j] = src[t + 512 * j];
            }
            __syncthreads();

            if (it > 0) {   // B-update for this slab's 16 s
                #pragma unroll 4
                for (int s8 = 0; s8 < 16; ++s8) {
                    const float4 l0 = *(const float4*)&sLc[s8][lane * 4];
                    const float4 l1 = *(const float4*)&sLc[s8][256 + lane * 4];
                    float pa = dot4(l0, ua0) + dot4(l1, ua1);
                    float pb = dot4(l0, ub0) + dot4(l1, ub1);
                    #pragma unroll
                    for (int m = 32; m >= 1; m >>= 1) {
                        pa += __shfl_xor(pa, m, 64);
                        pb += __shfl_xor(pb, m, 64);
                    }
                    if (lane == 0) {
                        sBc[ka][slab * 16 + s8] += pa;
                        sBc[kb][slab * 16 + s8] += pb;
                    }
                }
                __syncthreads();
            }

            if (t < 256) {  // softmax over k for slab's 16 s (16 lanes per s)
                const int si = t >> 4, k = t & 15, s = slab * 16 + si;
                const float v = sBc[k][s];
                float mx = v;
                #pragma unroll
                for (int m = 1; m < 16; m <<= 1) mx = fmaxf(mx, __shfl_xor(mx, m, 64));
                const float ex = expf(v - mx);
                float sm = ex;
                #pragma unroll
                for (int m = 1; m < 16; m <<= 1) sm += __shfl_xor(sm, m, 64);
                sWt[si][k] = ex * smask[s] / sm;
            }
            __syncthreads();

            // Z accumulate: thread does 4 k x 4 e over slab's 16 s
            #pragma unroll 4
            for (int si = 0; si < 16; ++si) {
                const float4 wv = *(const float4*)&sWt[si][k0];
                const float4 v  = *(const float4*)&sLc[si][e0];
                const f32x4 vv = {v.x, v.y, v.z, v.w};
                accZ[0] += vv * wv.x;
                accZ[1] += vv * wv.y;
                accZ[2] += vv * wv.z;
                accZ[3] += vv * wv.w;
            }
            __syncthreads();
        }

        #pragma unroll
        for (int ki = 0; ki < 4; ++ki) *(f32x4*)&sU[k0 + ki][e0] = accZ[ki];
        __syncthreads();

        // squash: wave w -> capsules 2w, 2w+1
        #pragma unroll
        for (int kk = ka; kk <= kb; ++kk) {
            float4 z0 = *(const float4*)&sU[kk][lane * 4];
            float4 z1 = *(const float4*)&sU[kk][256 + lane * 4];
            float p = dot4(z0, z0) + dot4(z1, z1);
            #pragma unroll
            for (int m = 32; m >= 1; m >>= 1) p += __shfl_xor(p, m, 64);
            const float sc = p / (1.0f + p) / sqrtf(p + 1e-9f);
            z0.x *= sc; z0.y *= sc; z0.z *= sc; z0.w *= sc;
            z1.x *= sc; z1.y *= sc; z1.z *= sc; z1.w *= sc;
            *(float4*)&sU[kk][lane * 4] = z0;
            *(float4*)&sU[kk][256 + lane * 4] = z1;
        }
        __syncthreads();
    }

    // pack final U -> bf16
    unsigned short* ub = Uh + (size_t)b * (KCAP * EMB);
    #pragma unroll
    for (int j = 0; j < 4; ++j) {
        const int f4 = t + 512 * j;
        const float4 v = ((const float4*)sU)[f4];
        u16x4 o;
        o[0] = f2bf(v.x); o[1] = f2bf(v.y); o[2] = f2bf(v.z); o[3] = f2bf(v.w);
        *(u16x4*)(ub + f4 * 4) = o;
    }
}

// ---------------------------------------------------------------------------
extern "C" void kernel_launch(void* const* d_in, const int* in_sizes, int n_in,
                              void* d_out, int out_size, void* d_ws, size_t ws_size,
                              hipStream_t stream) {
    const float* lc    = (const float*)d_in[0];  // [512,128,512]
    const float* Binit = (const float*)d_in[1];  // [512,16,128]
    const float* W_S   = (const float*)d_in[2];  // [512,512]
    const float* W_L   = (const float*)d_in[3];  // [512,512]
    const float* b_L   = (const float*)d_in[4];  // [512]
    const int*   valid = (const int*)d_in[5];    // [512,128]
    float* out = (float*)d_out;                  // [512,16,512]

    float* lcn = (float*)d_ws;                                   // 33,554,432 f32
    unsigned short* pkWS = (unsigned short*)(lcn + 33554432);    // 524,288 us
    unsigned short* pkWL = pkWS + 524288;                        // 524,288 us
    unsigned short* Uh   = pkWL + 524288;                        // 4,194,304 us
    if (ws_size < 144703488) return;

    cvt_pack<<<128, 256, 0, stream>>>(W_S, pkWS, 32768);
    cvt_pack<<<128, 256, 0, stream>>>(W_L, pkWL, 32768);
    // 1) lcn = lc @ W_S^T   (M=65536, 512 m-blocks x 4 n-blocks)
    gemm_f32a<<<2048, 256, 0, stream>>>(lc, pkWS, lcn);
    // 2) dynamic routing
    routing_v2<<<BATCH, 512, 0, stream>>>(lcn, Binit, valid, Uh);
    // 3) out = relu(U @ W_L^T + b_L)  (M=8192, 64 x 4)
    gemm_bf16a<<<256, 256, 0, stream>>>(Uh, pkWL, b_L, out);
}